// Round 20
// baseline (60.640 us; speedup 1.0000x reference)
//
#include <hip/hip_runtime.h>
#include <math.h>

#define HX 48
#define WX 48
#define OMC 216
#define HY 96
#define WY 96

typedef __attribute__((ext_vector_type(8))) short bf16x8;
typedef __attribute__((ext_vector_type(8))) unsigned short ushort8;
typedef __attribute__((ext_vector_type(4))) float f32x4;

__device__ inline unsigned short f2bf(float f) {
  unsigned u = __float_as_uint(f);
  return (unsigned short)((u + 0x7fffu + ((u >> 16) & 1u)) >> 16);  // RNE
}
__device__ inline unsigned pk2(float a, float b) {
  return (unsigned)f2bf(a) | ((unsigned)f2bf(b) << 16);
}
#define B2F(u) __uint_as_float((unsigned)(u) << 16)

// ws layout (floats):
//  om   @ 0          : 1,990,656
//  ap2  @ 1,990,656  :    73,728  (147,456 bf16)
//  ap1  @ 2,064,384  :    18,432  ( 36,864 bf16)
//  ytbf @ 2,082,816  : 1,179,648  (2,359,296 bf16: [b][g2=16][px9216][ch4])

// ---------- fused: prep (blocks 0..719) + ytr->bf16 half-group-major (720..1295) ----------
__global__ __launch_bounds__(256) void prep_ytr_kernel(
    const float* __restrict__ w_om, const float* __restrict__ w_dc,
    const float* __restrict__ y,
    unsigned short* __restrict__ ap2, unsigned short* __restrict__ ap1,
    unsigned short* __restrict__ ytbf) {
  __shared__ float tile[64][65];
  int bid = blockIdx.x;
  int t = threadIdx.x;
  if (bid < 720) {
    int idx = bid * 256 + t;                  // 0..184319
    if (idx < 147456) {
      int j = idx & 7;
      int tmp = idx >> 3;
      int l = tmp & 63; tmp >>= 6;
      int m = tmp & 15; tmp >>= 4;            // 0..17
      int s = tmp % 6, p = tmp / 6;
      int oc = m * 16 + (l & 15);
      int kk = s * 32 + (l >> 4) * 8 + j;     // 0..191
      int tap = kk >> 6, c = kk & 63;
      int k = p * 3 + tap;
      ap2[idx] = (oc < OMC) ? f2bf(w_om[oc * 576 + c * 9 + k]) : (unsigned short)0;
    } else {
      int i2 = idx - 147456;                  // < 36864
      int j = i2 & 7;
      int tmp = i2 >> 3;
      int l = tmp & 63; tmp >>= 6;
      int w = tmp & 3; tmp >>= 2;             // 0..17
      int s = tmp % 6, p = tmp / 6;
      int oc = w * 16 + (l & 15);
      int kk = s * 32 + (l >> 4) * 8 + j;
      int tap = kk >> 6, c = kk & 63;
      ap1[i2] = f2bf(w_dc[oc * 576 + c * 9 + p * 3 + tap]);
    }
  } else {
    int blk = bid - 720;                      // 576 = 4b * 144
    int b = blk / 144;
    int p0 = (blk % 144) * 64;
    int pl = t & 63;
    int cb = t >> 6;
#pragma unroll
    for (int i = 0; i < 16; ++i) {
      int c = cb * 16 + i;
      tile[c][pl] = y[((size_t)(b * 64 + c)) * 9216 + p0 + pl];
    }
    __syncthreads();
    int cw = t & 63;
    int pb = t >> 6;
#pragma unroll
    for (int i = 0; i < 16; ++i) {
      int p = pb * 16 + i;
      // half-group-major: [b][g2=cw>>2][px][c4=cw&3]
      ytbf[((size_t)((b * 16 + (cw >> 2)) * 9216) + p0 + p) * 4 + (cw & 3)] =
          f2bf(tile[cw][p]);
    }
  }
}

// ---------- conv (9 taps) via MFMA, oc-split; float4 register staging ----------
__global__ __launch_bounds__(256) void conv_mfma_kernel(
    const float* __restrict__ x, const unsigned short* __restrict__ ap2,
    const float* __restrict__ bom, float* __restrict__ om) {
  __shared__ unsigned short sB[9][16][72];    // 20736 B, [tap][px][c]
  int t = threadIdx.x;
  int bid = blockIdx.x;                       // 1152
  int logical = (bid & 7) * 144 + (bid >> 3); // bijective XCD swizzle
  int och = logical / 576;                    // oc half
  int rem = logical % 576;
  int b = rem / 144;
  int tl = rem % 144;
  int h0 = (tl / 12) * 4;
  int w0 = (tl % 12) * 4;
  int s_ic = t >> 2;
  int s_row = t & 3;
  const float* xp = x + (size_t)b * 64 * 2304 + (size_t)s_ic * 2304;

  float4 X[3][3];
  bool hvr[3];
#pragma unroll
  for (int r = 0; r < 3; ++r) {
    int hh = h0 + s_row + r - 1;
    hvr[r] = (unsigned)hh < (unsigned)HX;
    int hc = min(max(hh, 0), HX - 1);
    const float* xr = xp + hc * WX;
#pragma unroll
    for (int q = 0; q < 3; ++q) {
      int cb = min(max(w0 - 4 + 4 * q, 0), WX - 4);   // clamped aligned base
      X[r][q] = *(const float4*)&xr[cb];
    }
  }
#pragma unroll
  for (int k = 0; k < 9; ++k) {
    int dy = k / 3 - 1, dx = k % 3 - 1;
    int r = dy + 1;
#pragma unroll
    for (int j = 0; j < 4; ++j) {
      int idx = j + dx + 4;                   // column (w0+j+dx) -> idx 3..8
      int q = idx >> 2, e = idx & 3;
      float val = (e == 0) ? X[r][q].x : (e == 1) ? X[r][q].y
                : (e == 2) ? X[r][q].z : X[r][q].w;
      bool cv = (unsigned)(w0 + j + dx) < (unsigned)WX;
      float v = (hvr[r] && cv) ? val : 0.f;
      sB[k][s_row * 4 + j][s_ic] = f2bf(v);
    }
  }
  __syncthreads();

  int w = t >> 6;
  int l = t & 63;
  int lr = l & 15;
  int lg = l >> 4;
  f32x4 acc[2] = {};
#pragma unroll
  for (int p = 0; p < 3; ++p) {
#pragma unroll
    for (int s = 0; s < 6; ++s) {
      int tapidx = p * 3 + (s >> 1);
      int c0 = (s & 1) * 32;
      bf16x8 bv = *(const bf16x8*)&sB[tapidx][lr][c0 + lg * 8];
#pragma unroll
      for (int m = 0; m < 2; ++m) {
        int mq = och * 8 + w * 2 + m;         // 0..15
        bf16x8 av = *(const bf16x8*)(ap2 +
            (size_t)((((p * 6 + s) * 16) + mq) * 64 + l) * 8);
        acc[m] = __builtin_amdgcn_mfma_f32_16x16x32_bf16(av, bv, acc[m], 0, 0, 0);
      }
    }
  }
  int prow = lr >> 2, pcol = lr & 3;
#pragma unroll
  for (int m = 0; m < 2; ++m) {
    int ocb = (och * 8 + w * 2 + m) * 16 + lg * 4;
    if (ocb < OMC) {
      float4 bb = *(const float4*)&bom[ocb];
      float bvv[4] = {bb.x, bb.y, bb.z, bb.w};
#pragma unroll
      for (int i = 0; i < 4; ++i) {
        om[((size_t)(b * OMC + ocb + i)) * 2304 + (h0 + prow) * WX + w0 + pcol] =
            acc[m][i] + bvv[i];
      }
    }
  }
}

// ---------- deform: triples in LDS, x-pair 16B gather (2 loads/tap) + MFMA ----------
__global__ __launch_bounds__(256) void deform_mfma_kernel(
    const unsigned short* __restrict__ ytbf, const float* __restrict__ om,
    const unsigned short* __restrict__ ap1, const float* __restrict__ bdc,
    float* __restrict__ out) {
  __shared__ float sTy[72][16];                 // 4608 B  [k*8+g][px]
  __shared__ float sTx[72][16];                 // 4608 B
  __shared__ float sTm[72][16];                 // 4608 B
  __shared__ unsigned short sval[2][16][72];    // 4608 B   (total 18432 B)
  int t = threadIdx.x;
  int bid = blockIdx.x;                         // 2304
  int logical = (bid & 7) * 288 + (bid >> 3);   // bijective XCD swizzle
  int b = logical / 576;
  int tl = logical % 576;
  int h0 = (tl / 24) * 4;                       // 24 h-tiles of 4
  int w0 = (tl % 24) * 4;                       // 24 w-tiles of 4
  const float* omb = om + (size_t)b * OMC * 2304;

  // ---- Phase A: compute all 1152 resize triples once ----
#pragma unroll
  for (int r = 0; r < 5; ++r) {
    int j = t + r * 256;
    if (j < 1152) {
      int k = j >> 7;                           // 0..8
      int g = (j >> 4) & 7;
      int px = j & 15;
      int gh = h0 + (px >> 2);
      int gw = w0 + (px & 3);
      float sh = fmaxf(gh * 0.5f - 0.25f, 0.f);
      float sw = fmaxf(gw * 0.5f - 0.25f, 0.f);
      int i0h = (int)sh; float th = sh - (float)i0h;
      int i0w = (int)sw; float tw = sw - (float)i0w;
      int i1h = min(i0h + 1, HX - 1);
      int i1w = min(i0w + 1, WX - 1);
      float r00 = (1.f - th) * (1.f - tw), r01 = (1.f - th) * tw;
      float r10 = th * (1.f - tw),         r11 = th * tw;
      int a00 = i0h * WX + i0w, a01 = i0h * WX + i1w;
      int a10 = i1h * WX + i0w, a11 = i1h * WX + i1w;
      const float* cy = omb + (size_t)(g * 18 + k * 2) * 2304;
      const float* cx = cy + 2304;
      const float* cm = omb + (size_t)(144 + g * 9 + k) * 2304;
      float oy = r00 * cy[a00] + r01 * cy[a01] + r10 * cy[a10] + r11 * cy[a11];
      float ox = r00 * cx[a00] + r01 * cx[a01] + r10 * cx[a10] + r11 * cx[a11];
      float mv = r00 * cm[a00] + r01 * cm[a01] + r10 * cm[a10] + r11 * cm[a11];
      int row = k * 8 + g;
      sTy[row][px] = (float)(gh + k / 3 - 1) + oy;
      sTx[row][px] = (float)(gw + k % 3 - 1) + ox;
      sTm[row][px] = 1.f / (1.f + __expf(-mv));
    }
  }

  int item = t >> 1;                            // 0..127 = g*16 + px
  int g = item >> 4;
  int px = item & 15;
  int cp = t & 1;                               // channel half of the 8-ch group
  int chb = g * 8 + cp * 4;
  // half-group-major base: [b][g2=g*2+cp][px][ch4]
  const unsigned short* ytg =
      ytbf + (size_t)((b * 16 + g * 2 + cp) * 9216) * 4;

  int w = t >> 6;
  int l = t & 63;
  int lr = l & 15;
  int lg = l >> 4;

  __syncthreads();                              // triples ready

  ushort8 U[2][2];    // per slot: 2 row-pair loads (16B each)
  float W[2][4];      // per slot: {y0e0, y0e1, y1e0, y1e1}

  auto issueC = [&](int k, ushort8* Uo, float* Wo) {
    int row = k * 8 + g;
    float py = sTy[row][px], pxf = sTx[row][px], m = sTm[row][px];
    float y0f = floorf(py), x0f = floorf(pxf);
    float ty = py - y0f, tx = pxf - x0f;
    int y0 = (int)y0f, x0 = (int)x0f;
    int y1 = y0 + 1, x1 = x0 + 1;
    float w00 = (1.f - ty) * (1.f - tx) * m, w01 = (1.f - ty) * tx * m;
    float w10 = ty * (1.f - tx) * m,         w11 = ty * tx * m;
    bool xv0 = (unsigned)x0 < (unsigned)WY, xv1 = (unsigned)x1 < (unsigned)WY;
    bool yv0 = (unsigned)y0 < (unsigned)HY, yv1 = (unsigned)y1 < (unsigned)HY;
    int xb = min(max(x0, 0), WY - 2);           // pair base 0..94
    int i0 = x0 - xb;                           // -1, 0, +1 (or far OOB)
    bool s0n = (i0 == 0), sm1 = (i0 == -1), sp1 = (i0 == 1);
    float wa0 = xv0 ? w00 : 0.f, wb0 = xv1 ? w01 : 0.f;   // row y0
    float wa1 = xv0 ? w10 : 0.f, wb1 = xv1 ? w11 : 0.f;   // row y1
    Wo[0] = yv0 ? (s0n ? wa0 : (sm1 ? wb0 : 0.f)) : 0.f;  // y0, elem xb
    Wo[1] = yv0 ? (s0n ? wb0 : (sp1 ? wa0 : 0.f)) : 0.f;  // y0, elem xb+1
    Wo[2] = yv1 ? (s0n ? wa1 : (sm1 ? wb1 : 0.f)) : 0.f;  // y1, elem xb
    Wo[3] = yv1 ? (s0n ? wb1 : (sp1 ? wa1 : 0.f)) : 0.f;  // y1, elem xb+1
    int y0c = min(max(y0, 0), HY - 1), y1c = min(max(y1, 0), HY - 1);
    Uo[0] = *(const ushort8*)(ytg + ((size_t)(y0c * WY + xb) << 2));
    Uo[1] = *(const ushort8*)(ytg + ((size_t)(y1c * WY + xb) << 2));
  };
  auto finishC = [&](const ushort8* Ui, const float* Wi, int buf) {
    float4 s0;
    s0.x = Wi[0] * B2F(Ui[0][0]) + Wi[1] * B2F(Ui[0][4]) +
           Wi[2] * B2F(Ui[1][0]) + Wi[3] * B2F(Ui[1][4]);
    s0.y = Wi[0] * B2F(Ui[0][1]) + Wi[1] * B2F(Ui[0][5]) +
           Wi[2] * B2F(Ui[1][1]) + Wi[3] * B2F(Ui[1][5]);
    s0.z = Wi[0] * B2F(Ui[0][2]) + Wi[1] * B2F(Ui[0][6]) +
           Wi[2] * B2F(Ui[1][2]) + Wi[3] * B2F(Ui[1][6]);
    s0.w = Wi[0] * B2F(Ui[0][3]) + Wi[1] * B2F(Ui[0][7]) +
           Wi[2] * B2F(Ui[1][3]) + Wi[3] * B2F(Ui[1][7]);
    *(uint2*)&sval[buf][px][chb] = make_uint2(pk2(s0.x, s0.y), pk2(s0.z, s0.w));
  };

  // prologue: tap 0 pair loads in flight (pinned — may not sink)
  issueC(0, U[0], W[0]);
  __builtin_amdgcn_sched_barrier(0);

  f32x4 acc = {};
#pragma unroll
  for (int tp = 0; tp < 9; ++tp) {
    if (tp + 1 < 9) {                            // next tap: 1-iter flight
      issueC(tp + 1, U[(tp + 1) & 1], W[(tp + 1) & 1]);
      __builtin_amdgcn_sched_barrier(0);         // pin loads BEFORE finishC(tp)
    }
    finishC(U[tp & 1], W[tp & 1], tp & 1);       // issued last iter
    __syncthreads();
    int p = tp / 3;
    int sl = (tp % 3) * 2;
#pragma unroll
    for (int half = 0; half < 2; ++half) {
      int s = sl + half;
      bf16x8 av = *(const bf16x8*)(ap1 +
          (size_t)(((p * 6 + s) * 4 + w) * 64 + l) * 8);
      bf16x8 bv = *(const bf16x8*)&sval[tp & 1][lr][half * 32 + lg * 8];
      acc = __builtin_amdgcn_mfma_f32_16x16x32_bf16(av, bv, acc, 0, 0, 0);
    }
    // finishC[tp+2] (same buf) is fenced by barrier[tp+1] which program-order
    // follows this MFMA's LDS reads on every wave.
  }

  // epilogue: bias + relu + store (oc = w*16+lg*4+i, px = lr in 4x4 tile)
  float4 bb = *(const float4*)&bdc[w * 16 + lg * 4];
  float bvv[4] = {bb.x, bb.y, bb.z, bb.w};
#pragma unroll
  for (int i = 0; i < 4; ++i) {
    int oc = w * 16 + lg * 4 + i;
    out[((size_t)(b * 64 + oc) * 96 + h0 + (lr >> 2)) * 96 + w0 + (lr & 3)] =
        fmaxf(acc[i] + bvv[i], 0.f);
  }
}

extern "C" void kernel_launch(void* const* d_in, const int* in_sizes, int n_in,
                              void* d_out, int out_size, void* d_ws, size_t ws_size,
                              hipStream_t stream) {
  const float* x = (const float*)d_in[0];
  const float* y = (const float*)d_in[1];
  const float* w_om = (const float*)d_in[2];
  const float* b_om = (const float*)d_in[3];
  const float* w_dc = (const float*)d_in[4];
  const float* b_dc = (const float*)d_in[5];
  float* out = (float*)d_out;

  float* om  = (float*)d_ws;                       // 1,990,656 f
  unsigned short* ap2 = (unsigned short*)(om + 1990656);   // 147,456 bf16
  unsigned short* ap1 = ap2 + 147456;              //  36,864 bf16
  unsigned short* ytbf = ap1 + 36864;              // 2,359,296 bf16

  prep_ytr_kernel<<<1296, 256, 0, stream>>>(w_om, w_dc, y, ap2, ap1, ytbf);
  conv_mfma_kernel<<<1152, 256, 0, stream>>>(x, ap2, b_om, om);
  deform_mfma_kernel<<<2304, 256, 0, stream>>>(ytbf, om, ap1, b_dc, out);
}

// Round 21
// 57.805 us; speedup vs baseline: 1.0491x; 1.0491x over previous
//
#include <hip/hip_runtime.h>
#include <math.h>

#define HX 48
#define WX 48
#define OMC 216
#define HY 96
#define WY 96

typedef __attribute__((ext_vector_type(8))) short bf16x8;
typedef __attribute__((ext_vector_type(4))) float f32x4;

__device__ inline unsigned short f2bf(float f) {
  unsigned u = __float_as_uint(f);
  return (unsigned short)((u + 0x7fffu + ((u >> 16) & 1u)) >> 16);  // RNE
}
__device__ inline unsigned pk2(float a, float b) {
  return (unsigned)f2bf(a) | ((unsigned)f2bf(b) << 16);
}
#define B2F(u) __uint_as_float((unsigned)(u) << 16)

// ws layout (floats):
//  om   @ 0          : 1,990,656
//  ap2  @ 1,990,656  :    73,728  (147,456 bf16)
//  ap1  @ 2,064,384  :    18,432  ( 36,864 bf16)
//  ytbf @ 2,082,816  : 1,179,648  (2,359,296 bf16: [b][g8][px9216][ch8])

// ---------- fused: prep (blocks 0..719) + ytr->bf16 group-major (720..1295) ----------
__global__ __launch_bounds__(256) void prep_ytr_kernel(
    const float* __restrict__ w_om, const float* __restrict__ w_dc,
    const float* __restrict__ y,
    unsigned short* __restrict__ ap2, unsigned short* __restrict__ ap1,
    unsigned short* __restrict__ ytbf) {
  __shared__ float tile[64][65];
  int bid = blockIdx.x;
  int t = threadIdx.x;
  if (bid < 720) {
    int idx = bid * 256 + t;                  // 0..184319
    if (idx < 147456) {
      int j = idx & 7;
      int tmp = idx >> 3;
      int l = tmp & 63; tmp >>= 6;
      int m = tmp & 15; tmp >>= 4;            // 0..17
      int s = tmp % 6, p = tmp / 6;
      int oc = m * 16 + (l & 15);
      int kk = s * 32 + (l >> 4) * 8 + j;     // 0..191
      int tap = kk >> 6, c = kk & 63;
      int k = p * 3 + tap;
      ap2[idx] = (oc < OMC) ? f2bf(w_om[oc * 576 + c * 9 + k]) : (unsigned short)0;
    } else {
      int i2 = idx - 147456;                  // < 36864
      int j = i2 & 7;
      int tmp = i2 >> 3;
      int l = tmp & 63; tmp >>= 6;
      int w = tmp & 3; tmp >>= 2;             // 0..17
      int s = tmp % 6, p = tmp / 6;
      int oc = w * 16 + (l & 15);
      int kk = s * 32 + (l >> 4) * 8 + j;
      int tap = kk >> 6, c = kk & 63;
      ap1[i2] = f2bf(w_dc[oc * 576 + c * 9 + p * 3 + tap]);
    }
  } else {
    int blk = bid - 720;                      // 576 = 4b * 144
    int b = blk / 144;
    int p0 = (blk % 144) * 64;
    int pl = t & 63;
    int cb = t >> 6;
#pragma unroll
    for (int i = 0; i < 16; ++i) {
      int c = cb * 16 + i;
      tile[c][pl] = y[((size_t)(b * 64 + c)) * 9216 + p0 + pl];
    }
    __syncthreads();
    int cw = t & 63;
    int pb = t >> 6;
#pragma unroll
    for (int i = 0; i < 16; ++i) {
      int p = pb * 16 + i;
      // group-major: [b][g][px][c8]
      ytbf[((size_t)((b * 8 + (cw >> 3)) * 9216) + p0 + p) * 8 + (cw & 7)] =
          f2bf(tile[cw][p]);
    }
  }
}

// ---------- conv (9 taps) via MFMA, oc-split; float4 register staging ----------
__global__ __launch_bounds__(256) void conv_mfma_kernel(
    const float* __restrict__ x, const unsigned short* __restrict__ ap2,
    const float* __restrict__ bom, float* __restrict__ om) {
  __shared__ unsigned short sB[9][16][72];    // 20736 B, [tap][px][c]
  int t = threadIdx.x;
  int bid = blockIdx.x;                       // 1152
  int logical = (bid & 7) * 144 + (bid >> 3); // bijective XCD swizzle
  int och = logical / 576;                    // oc half
  int rem = logical % 576;
  int b = rem / 144;
  int tl = rem % 144;
  int h0 = (tl / 12) * 4;
  int w0 = (tl % 12) * 4;
  int s_ic = t >> 2;
  int s_row = t & 3;
  const float* xp = x + (size_t)b * 64 * 2304 + (size_t)s_ic * 2304;

  float4 X[3][3];
  bool hvr[3];
#pragma unroll
  for (int r = 0; r < 3; ++r) {
    int hh = h0 + s_row + r - 1;
    hvr[r] = (unsigned)hh < (unsigned)HX;
    int hc = min(max(hh, 0), HX - 1);
    const float* xr = xp + hc * WX;
#pragma unroll
    for (int q = 0; q < 3; ++q) {
      int cb = min(max(w0 - 4 + 4 * q, 0), WX - 4);   // clamped aligned base
      X[r][q] = *(const float4*)&xr[cb];
    }
  }
#pragma unroll
  for (int k = 0; k < 9; ++k) {
    int dy = k / 3 - 1, dx = k % 3 - 1;
    int r = dy + 1;
#pragma unroll
    for (int j = 0; j < 4; ++j) {
      int idx = j + dx + 4;                   // column (w0+j+dx) -> idx 3..8
      int q = idx >> 2, e = idx & 3;
      float val = (e == 0) ? X[r][q].x : (e == 1) ? X[r][q].y
                : (e == 2) ? X[r][q].z : X[r][q].w;
      bool cv = (unsigned)(w0 + j + dx) < (unsigned)WX;
      float v = (hvr[r] && cv) ? val : 0.f;
      sB[k][s_row * 4 + j][s_ic] = f2bf(v);
    }
  }
  __syncthreads();

  int w = t >> 6;
  int l = t & 63;
  int lr = l & 15;
  int lg = l >> 4;
  f32x4 acc[2] = {};
#pragma unroll
  for (int p = 0; p < 3; ++p) {
#pragma unroll
    for (int s = 0; s < 6; ++s) {
      int tapidx = p * 3 + (s >> 1);
      int c0 = (s & 1) * 32;
      bf16x8 bv = *(const bf16x8*)&sB[tapidx][lr][c0 + lg * 8];
#pragma unroll
      for (int m = 0; m < 2; ++m) {
        int mq = och * 8 + w * 2 + m;         // 0..15
        bf16x8 av = *(const bf16x8*)(ap2 +
            (size_t)((((p * 6 + s) * 16) + mq) * 64 + l) * 8);
        acc[m] = __builtin_amdgcn_mfma_f32_16x16x32_bf16(av, bv, acc[m], 0, 0, 0);
      }
    }
  }
  int prow = lr >> 2, pcol = lr & 3;
#pragma unroll
  for (int m = 0; m < 2; ++m) {
    int ocb = (och * 8 + w * 2 + m) * 16 + lg * 4;
    if (ocb < OMC) {
      float4 bb = *(const float4*)&bom[ocb];
      float bvv[4] = {bb.x, bb.y, bb.z, bb.w};
#pragma unroll
      for (int i = 0; i < 4; ++i) {
        om[((size_t)(b * OMC + ocb + i)) * 2304 + (h0 + prow) * WX + w0 + pcol] =
            acc[m][i] + bvv[i];
      }
    }
  }
}

// ---------- deform: triples in LDS, 2-deep pipelined group-major gather + MFMA ----------
__global__ __launch_bounds__(256) void deform_mfma_kernel(
    const unsigned short* __restrict__ ytbf, const float* __restrict__ om,
    const unsigned short* __restrict__ ap1, const float* __restrict__ bdc,
    float* __restrict__ out) {
  __shared__ float sTy[72][16];                 // 4608 B  [k*8+g][px]
  __shared__ float sTx[72][16];                 // 4608 B
  __shared__ float sTm[72][16];                 // 4608 B
  __shared__ unsigned short sval[2][16][72];    // 4608 B   (total 18432 B)
  int t = threadIdx.x;
  int bid = blockIdx.x;                         // 2304
  int logical = (bid & 7) * 288 + (bid >> 3);   // bijective XCD swizzle
  int b = logical / 576;
  int tl = logical % 576;
  int h0 = (tl / 24) * 4;                       // 24 h-tiles of 4
  int w0 = (tl % 24) * 4;                       // 24 w-tiles of 4
  const float* omb = om + (size_t)b * OMC * 2304;

  // ---- Phase A: compute all 1152 resize triples once ----
#pragma unroll
  for (int r = 0; r < 5; ++r) {
    int j = t + r * 256;
    if (j < 1152) {
      int k = j >> 7;                           // 0..8
      int g = (j >> 4) & 7;
      int px = j & 15;
      int gh = h0 + (px >> 2);
      int gw = w0 + (px & 3);
      float sh = fmaxf(gh * 0.5f - 0.25f, 0.f);
      float sw = fmaxf(gw * 0.5f - 0.25f, 0.f);
      int i0h = (int)sh; float th = sh - (float)i0h;
      int i0w = (int)sw; float tw = sw - (float)i0w;
      int i1h = min(i0h + 1, HX - 1);
      int i1w = min(i0w + 1, WX - 1);
      float r00 = (1.f - th) * (1.f - tw), r01 = (1.f - th) * tw;
      float r10 = th * (1.f - tw),         r11 = th * tw;
      int a00 = i0h * WX + i0w, a01 = i0h * WX + i1w;
      int a10 = i1h * WX + i0w, a11 = i1h * WX + i1w;
      const float* cy = omb + (size_t)(g * 18 + k * 2) * 2304;
      const float* cx = cy + 2304;
      const float* cm = omb + (size_t)(144 + g * 9 + k) * 2304;
      float oy = r00 * cy[a00] + r01 * cy[a01] + r10 * cy[a10] + r11 * cy[a11];
      float ox = r00 * cx[a00] + r01 * cx[a01] + r10 * cx[a10] + r11 * cx[a11];
      float mv = r00 * cm[a00] + r01 * cm[a01] + r10 * cm[a10] + r11 * cm[a11];
      int row = k * 8 + g;
      sTy[row][px] = (float)(gh + k / 3 - 1) + oy;
      sTx[row][px] = (float)(gw + k % 3 - 1) + ox;
      sTm[row][px] = 1.f / (1.f + __expf(-mv));
    }
  }

  int item = t >> 1;                            // 0..127 = g*16 + px
  int g = item >> 4;
  int px = item & 15;
  int cp = t & 1;                               // channel half of the 8-ch group
  int chb = g * 8 + cp * 4;
  // group-major base for this item's group, channel-half cp
  const unsigned short* ytg =
      ytbf + ((size_t)(b * 8 + g) * 9216) * 8 + cp * 4;

  int w = t >> 6;
  int l = t & 63;
  int lr = l & 15;
  int lg = l >> 4;

  __syncthreads();                              // triples ready

  ushort4 U[3][4];    // corner bf16x4 loads, 3-slot rotation (2 taps in flight)
  float W[3][4];      // corner weights

  auto issueC = [&](int k, ushort4* Uo, float* Wo) {
    int row = k * 8 + g;
    float py = sTy[row][px], pxf = sTx[row][px], m = sTm[row][px];
    float y0f = floorf(py), x0f = floorf(pxf);
    float ty = py - y0f, tx = pxf - x0f;
    int y0 = (int)y0f, x0 = (int)x0f;
    int y1 = y0 + 1, x1 = x0 + 1;
    float w00 = (1.f - ty) * (1.f - tx) * m, w01 = (1.f - ty) * tx * m;
    float w10 = ty * (1.f - tx) * m,         w11 = ty * tx * m;
    Wo[0] = ((unsigned)y0 < HY && (unsigned)x0 < WY) ? w00 : 0.f;
    Wo[1] = ((unsigned)y0 < HY && (unsigned)x1 < WY) ? w01 : 0.f;
    Wo[2] = ((unsigned)y1 < HY && (unsigned)x0 < WY) ? w10 : 0.f;
    Wo[3] = ((unsigned)y1 < HY && (unsigned)x1 < WY) ? w11 : 0.f;
    int y0c = min(max(y0, 0), HY - 1), y1c = min(max(y1, 0), HY - 1);
    int x0c = min(max(x0, 0), WY - 1), x1c = min(max(x1, 0), WY - 1);
    Uo[0] = *(const ushort4*)(ytg + ((size_t)(y0c * WY + x0c) << 3));
    Uo[1] = *(const ushort4*)(ytg + ((size_t)(y0c * WY + x1c) << 3));
    Uo[2] = *(const ushort4*)(ytg + ((size_t)(y1c * WY + x0c) << 3));
    Uo[3] = *(const ushort4*)(ytg + ((size_t)(y1c * WY + x1c) << 3));
  };
  auto finishC = [&](const ushort4* Ui, const float* Wi, int buf) {
    float4 s0 = {0.f, 0.f, 0.f, 0.f};
#pragma unroll
    for (int c4 = 0; c4 < 4; ++c4) {
      float wgt = Wi[c4];
      s0.x += wgt * B2F(Ui[c4].x);
      s0.y += wgt * B2F(Ui[c4].y);
      s0.z += wgt * B2F(Ui[c4].z);
      s0.w += wgt * B2F(Ui[c4].w);
    }
    *(uint2*)&sval[buf][px][chb] = make_uint2(pk2(s0.x, s0.y), pk2(s0.z, s0.w));
  };

  // prologue: taps 0 and 1 in flight (pinned — may not sink)
  issueC(0, U[0], W[0]);
  __builtin_amdgcn_sched_barrier(0);
  issueC(1, U[1], W[1]);
  __builtin_amdgcn_sched_barrier(0);

  f32x4 acc = {};
#pragma unroll
  for (int tp = 0; tp < 9; ++tp) {
    if (tp + 2 < 9) {                            // 2-iter flight
      issueC(tp + 2, U[(tp + 2) % 3], W[(tp + 2) % 3]);
      __builtin_amdgcn_sched_barrier(0);         // pin loads BEFORE finishC(tp)
    }
    finishC(U[tp % 3], W[tp % 3], tp & 1);       // issued 2 iters ago
    __syncthreads();
    int p = tp / 3;
    int sl = (tp % 3) * 2;
#pragma unroll
    for (int half = 0; half < 2; ++half) {
      int s = sl + half;
      bf16x8 av = *(const bf16x8*)(ap1 +
          (size_t)(((p * 6 + s) * 4 + w) * 64 + l) * 8);
      bf16x8 bv = *(const bf16x8*)&sval[tp & 1][lr][half * 32 + lg * 8];
      acc = __builtin_amdgcn_mfma_f32_16x16x32_bf16(av, bv, acc, 0, 0, 0);
    }
    // finishC[tp+2] (same buf) is fenced by barrier[tp+1] which program-order
    // follows this MFMA's LDS reads on every wave.
  }

  // epilogue: bias + relu + store (oc = w*16+lg*4+i, px = lr in 4x4 tile)
  float4 bb = *(const float4*)&bdc[w * 16 + lg * 4];
  float bvv[4] = {bb.x, bb.y, bb.z, bb.w};
#pragma unroll
  for (int i = 0; i < 4; ++i) {
    int oc = w * 16 + lg * 4 + i;
    out[((size_t)(b * 64 + oc) * 96 + h0 + (lr >> 2)) * 96 + w0 + (lr & 3)] =
        fmaxf(acc[i] + bvv[i], 0.f);
  }
}

extern "C" void kernel_launch(void* const* d_in, const int* in_sizes, int n_in,
                              void* d_out, int out_size, void* d_ws, size_t ws_size,
                              hipStream_t stream) {
  const float* x = (const float*)d_in[0];
  const float* y = (const float*)d_in[1];
  const float* w_om = (const float*)d_in[2];
  const float* b_om = (const float*)d_in[3];
  const float* w_dc = (const float*)d_in[4];
  const float* b_dc = (const float*)d_in[5];
  float* out = (float*)d_out;

  float* om  = (float*)d_ws;                       // 1,990,656 f
  unsigned short* ap2 = (unsigned short*)(om + 1990656);   // 147,456 bf16
  unsigned short* ap1 = ap2 + 147456;              //  36,864 bf16
  unsigned short* ytbf = ap1 + 36864;              // 2,359,296 bf16

  prep_ytr_kernel<<<1296, 256, 0, stream>>>(w_om, w_dc, y, ap2, ap1, ytbf);
  conv_mfma_kernel<<<1152, 256, 0, stream>>>(x, ap2, b_om, om);
  deform_mfma_kernel<<<2304, 256, 0, stream>>>(ytbf, om, ap1, b_dc, out);
}

// Round 22
// 57.539 us; speedup vs baseline: 1.0539x; 1.0046x over previous
//
#include <hip/hip_runtime.h>
#include <math.h>

#define HX 48
#define WX 48
#define OMC 216
#define HY 96
#define WY 96

typedef __attribute__((ext_vector_type(8))) short bf16x8;
typedef __attribute__((ext_vector_type(4))) float f32x4;

__device__ inline unsigned short f2bf(float f) {
  unsigned u = __float_as_uint(f);
  return (unsigned short)((u + 0x7fffu + ((u >> 16) & 1u)) >> 16);  // RNE
}
__device__ inline unsigned pk2(float a, float b) {
  return (unsigned)f2bf(a) | ((unsigned)f2bf(b) << 16);
}
#define B2F(u) __uint_as_float((unsigned)(u) << 16)

// ws layout (floats):
//  om   @ 0          : 1,990,656
//  ap2  @ 1,990,656  :    73,728  (147,456 bf16)
//  ap1  @ 2,064,384  :    18,432  ( 36,864 bf16)
//  ytbf @ 2,082,816  : 1,179,648  (2,359,296 bf16: [b][g8][px9216][ch8])

// ---------- fused: prep (blocks 0..719) + ytr->bf16 group-major (720..1295) ----------
__global__ __launch_bounds__(256) void prep_ytr_kernel(
    const float* __restrict__ w_om, const float* __restrict__ w_dc,
    const float* __restrict__ y,
    unsigned short* __restrict__ ap2, unsigned short* __restrict__ ap1,
    unsigned short* __restrict__ ytbf) {
  __shared__ float tile[64][65];
  int bid = blockIdx.x;
  int t = threadIdx.x;
  if (bid < 720) {
    int idx = bid * 256 + t;                  // 0..184319
    if (idx < 147456) {
      int j = idx & 7;
      int tmp = idx >> 3;
      int l = tmp & 63; tmp >>= 6;
      int m = tmp & 15; tmp >>= 4;            // 0..17
      int s = tmp % 6, p = tmp / 6;
      int oc = m * 16 + (l & 15);
      int kk = s * 32 + (l >> 4) * 8 + j;     // 0..191
      int tap = kk >> 6, c = kk & 63;
      int k = p * 3 + tap;
      ap2[idx] = (oc < OMC) ? f2bf(w_om[oc * 576 + c * 9 + k]) : (unsigned short)0;
    } else {
      int i2 = idx - 147456;                  // < 36864
      int j = i2 & 7;
      int tmp = i2 >> 3;
      int l = tmp & 63; tmp >>= 6;
      int w = tmp & 3; tmp >>= 2;             // 0..17
      int s = tmp % 6, p = tmp / 6;
      int oc = w * 16 + (l & 15);
      int kk = s * 32 + (l >> 4) * 8 + j;
      int tap = kk >> 6, c = kk & 63;
      ap1[i2] = f2bf(w_dc[oc * 576 + c * 9 + p * 3 + tap]);
    }
  } else {
    int blk = bid - 720;                      // 576 = 4b * 144
    int b = blk / 144;
    int p0 = (blk % 144) * 64;
    int pl = t & 63;
    int cb = t >> 6;
#pragma unroll
    for (int i = 0; i < 16; ++i) {
      int c = cb * 16 + i;
      tile[c][pl] = y[((size_t)(b * 64 + c)) * 9216 + p0 + pl];
    }
    __syncthreads();
    int cw = t & 63;
    int pb = t >> 6;
#pragma unroll
    for (int i = 0; i < 16; ++i) {
      int p = pb * 16 + i;
      // group-major: [b][g][px][c8]
      ytbf[((size_t)((b * 8 + (cw >> 3)) * 9216) + p0 + p) * 8 + (cw & 7)] =
          f2bf(tile[cw][p]);
    }
  }
}

// ---------- conv (9 taps) via MFMA, oc-split; float4 register staging ----------
__global__ __launch_bounds__(256) void conv_mfma_kernel(
    const float* __restrict__ x, const unsigned short* __restrict__ ap2,
    const float* __restrict__ bom, float* __restrict__ om) {
  __shared__ unsigned short sB[9][16][72];    // 20736 B, [tap][px][c]
  int t = threadIdx.x;
  int bid = blockIdx.x;                       // 1152
  int logical = (bid & 7) * 144 + (bid >> 3); // bijective XCD swizzle
  int och = logical / 576;                    // oc half
  int rem = logical % 576;
  int b = rem / 144;
  int tl = rem % 144;
  int h0 = (tl / 12) * 4;
  int w0 = (tl % 12) * 4;
  int s_ic = t >> 2;
  int s_row = t & 3;
  const float* xp = x + (size_t)b * 64 * 2304 + (size_t)s_ic * 2304;

  float4 X[3][3];
  bool hvr[3];
#pragma unroll
  for (int r = 0; r < 3; ++r) {
    int hh = h0 + s_row + r - 1;
    hvr[r] = (unsigned)hh < (unsigned)HX;
    int hc = min(max(hh, 0), HX - 1);
    const float* xr = xp + hc * WX;
#pragma unroll
    for (int q = 0; q < 3; ++q) {
      int cb = min(max(w0 - 4 + 4 * q, 0), WX - 4);   // clamped aligned base
      X[r][q] = *(const float4*)&xr[cb];
    }
  }
#pragma unroll
  for (int k = 0; k < 9; ++k) {
    int dy = k / 3 - 1, dx = k % 3 - 1;
    int r = dy + 1;
#pragma unroll
    for (int j = 0; j < 4; ++j) {
      int idx = j + dx + 4;                   // column (w0+j+dx) -> idx 3..8
      int q = idx >> 2, e = idx & 3;
      float val = (e == 0) ? X[r][q].x : (e == 1) ? X[r][q].y
                : (e == 2) ? X[r][q].z : X[r][q].w;
      bool cv = (unsigned)(w0 + j + dx) < (unsigned)WX;
      float v = (hvr[r] && cv) ? val : 0.f;
      sB[k][s_row * 4 + j][s_ic] = f2bf(v);
    }
  }
  __syncthreads();

  int w = t >> 6;
  int l = t & 63;
  int lr = l & 15;
  int lg = l >> 4;
  f32x4 acc[2] = {};
#pragma unroll
  for (int p = 0; p < 3; ++p) {
#pragma unroll
    for (int s = 0; s < 6; ++s) {
      int tapidx = p * 3 + (s >> 1);
      int c0 = (s & 1) * 32;
      bf16x8 bv = *(const bf16x8*)&sB[tapidx][lr][c0 + lg * 8];
#pragma unroll
      for (int m = 0; m < 2; ++m) {
        int mq = och * 8 + w * 2 + m;         // 0..15
        bf16x8 av = *(const bf16x8*)(ap2 +
            (size_t)((((p * 6 + s) * 16) + mq) * 64 + l) * 8);
        acc[m] = __builtin_amdgcn_mfma_f32_16x16x32_bf16(av, bv, acc[m], 0, 0, 0);
      }
    }
  }
  int prow = lr >> 2, pcol = lr & 3;
#pragma unroll
  for (int m = 0; m < 2; ++m) {
    int ocb = (och * 8 + w * 2 + m) * 16 + lg * 4;
    if (ocb < OMC) {
      float4 bb = *(const float4*)&bom[ocb];
      float bvv[4] = {bb.x, bb.y, bb.z, bb.w};
#pragma unroll
      for (int i = 0; i < 4; ++i) {
        om[((size_t)(b * OMC + ocb + i)) * 2304 + (h0 + prow) * WX + w0 + pcol] =
            acc[m][i] + bvv[i];
      }
    }
  }
}

// ---------- deform: triples in LDS, 3-tap-burst gather + MFMA ----------
__global__ __launch_bounds__(256) void deform_mfma_kernel(
    const unsigned short* __restrict__ ytbf, const float* __restrict__ om,
    const unsigned short* __restrict__ ap1, const float* __restrict__ bdc,
    float* __restrict__ out) {
  __shared__ float sTy[72][16];                 // 4608 B  [k*8+g][px]
  __shared__ float sTx[72][16];                 // 4608 B
  __shared__ float sTm[72][16];                 // 4608 B
  __shared__ unsigned short sval[3][16][72];    // 6912 B   (total 20736 B)
  int t = threadIdx.x;
  int bid = blockIdx.x;                         // 2304
  int logical = (bid & 7) * 288 + (bid >> 3);   // bijective XCD swizzle
  int b = logical / 576;
  int tl = logical % 576;
  int h0 = (tl / 24) * 4;                       // 24 h-tiles of 4
  int w0 = (tl % 24) * 4;                       // 24 w-tiles of 4
  const float* omb = om + (size_t)b * OMC * 2304;

  // ---- Phase A: compute all 1152 resize triples once ----
#pragma unroll
  for (int r = 0; r < 5; ++r) {
    int j = t + r * 256;
    if (j < 1152) {
      int k = j >> 7;                           // 0..8
      int g = (j >> 4) & 7;
      int px = j & 15;
      int gh = h0 + (px >> 2);
      int gw = w0 + (px & 3);
      float sh = fmaxf(gh * 0.5f - 0.25f, 0.f);
      float sw = fmaxf(gw * 0.5f - 0.25f, 0.f);
      int i0h = (int)sh; float th = sh - (float)i0h;
      int i0w = (int)sw; float tw = sw - (float)i0w;
      int i1h = min(i0h + 1, HX - 1);
      int i1w = min(i0w + 1, WX - 1);
      float r00 = (1.f - th) * (1.f - tw), r01 = (1.f - th) * tw;
      float r10 = th * (1.f - tw),         r11 = th * tw;
      int a00 = i0h * WX + i0w, a01 = i0h * WX + i1w;
      int a10 = i1h * WX + i0w, a11 = i1h * WX + i1w;
      const float* cy = omb + (size_t)(g * 18 + k * 2) * 2304;
      const float* cx = cy + 2304;
      const float* cm = omb + (size_t)(144 + g * 9 + k) * 2304;
      float oy = r00 * cy[a00] + r01 * cy[a01] + r10 * cy[a10] + r11 * cy[a11];
      float ox = r00 * cx[a00] + r01 * cx[a01] + r10 * cx[a10] + r11 * cx[a11];
      float mv = r00 * cm[a00] + r01 * cm[a01] + r10 * cm[a10] + r11 * cm[a11];
      int row = k * 8 + g;
      sTy[row][px] = (float)(gh + k / 3 - 1) + oy;
      sTx[row][px] = (float)(gw + k % 3 - 1) + ox;
      sTm[row][px] = 1.f / (1.f + __expf(-mv));
    }
  }

  int item = t >> 1;                            // 0..127 = g*16 + px
  int g = item >> 4;
  int px = item & 15;
  int cp = t & 1;                               // channel half of the 8-ch group
  int chb = g * 8 + cp * 4;
  // group-major base for this item's group, channel-half cp
  const unsigned short* ytg =
      ytbf + ((size_t)(b * 8 + g) * 9216) * 8 + cp * 4;

  int w = t >> 6;
  int l = t & 63;
  int lr = l & 15;
  int lg = l >> 4;

  __syncthreads();                              // triples ready

  ushort4 U[12];      // 12 corner loads in flight (one 3-tap burst)
  float W[12];        // corner weights

  auto issueC = [&](int k, ushort4* Uo, float* Wo) {
    int row = k * 8 + g;
    float py = sTy[row][px], pxf = sTx[row][px], m = sTm[row][px];
    float y0f = floorf(py), x0f = floorf(pxf);
    float ty = py - y0f, tx = pxf - x0f;
    int y0 = (int)y0f, x0 = (int)x0f;
    int y1 = y0 + 1, x1 = x0 + 1;
    float w00 = (1.f - ty) * (1.f - tx) * m, w01 = (1.f - ty) * tx * m;
    float w10 = ty * (1.f - tx) * m,         w11 = ty * tx * m;
    Wo[0] = ((unsigned)y0 < HY && (unsigned)x0 < WY) ? w00 : 0.f;
    Wo[1] = ((unsigned)y0 < HY && (unsigned)x1 < WY) ? w01 : 0.f;
    Wo[2] = ((unsigned)y1 < HY && (unsigned)x0 < WY) ? w10 : 0.f;
    Wo[3] = ((unsigned)y1 < HY && (unsigned)x1 < WY) ? w11 : 0.f;
    int y0c = min(max(y0, 0), HY - 1), y1c = min(max(y1, 0), HY - 1);
    int x0c = min(max(x0, 0), WY - 1), x1c = min(max(x1, 0), WY - 1);
    Uo[0] = *(const ushort4*)(ytg + ((size_t)(y0c * WY + x0c) << 3));
    Uo[1] = *(const ushort4*)(ytg + ((size_t)(y0c * WY + x1c) << 3));
    Uo[2] = *(const ushort4*)(ytg + ((size_t)(y1c * WY + x0c) << 3));
    Uo[3] = *(const ushort4*)(ytg + ((size_t)(y1c * WY + x1c) << 3));
  };
  auto finishC = [&](const ushort4* Ui, const float* Wi, int buf) {
    float4 s0 = {0.f, 0.f, 0.f, 0.f};
#pragma unroll
    for (int c4 = 0; c4 < 4; ++c4) {
      float wgt = Wi[c4];
      s0.x += wgt * B2F(Ui[c4].x);
      s0.y += wgt * B2F(Ui[c4].y);
      s0.z += wgt * B2F(Ui[c4].z);
      s0.w += wgt * B2F(Ui[c4].w);
    }
    *(uint2*)&sval[buf][px][chb] = make_uint2(pk2(s0.x, s0.y), pk2(s0.z, s0.w));
  };

  // prologue: burst 0 (taps 0..2) loads in flight
#pragma unroll
  for (int tt = 0; tt < 3; ++tt) issueC(tt, &U[4 * tt], &W[4 * tt]);
  __builtin_amdgcn_sched_barrier(0);

  f32x4 acc = {};
#pragma unroll
  for (int j = 0; j < 3; ++j) {
    // finish burst j (consumes U/W), then refill U/W with burst j+1
#pragma unroll
    for (int tt = 0; tt < 3; ++tt) finishC(&U[4 * tt], &W[4 * tt], tt);
    if (j < 2) {
#pragma unroll
      for (int tt = 0; tt < 3; ++tt)
        issueC(3 * (j + 1) + tt, &U[4 * tt], &W[4 * tt]);
      __builtin_amdgcn_sched_barrier(0);         // pin refill above the barrier
    }
    __syncthreads();                             // sval[0..2] ready
#pragma unroll
    for (int tt = 0; tt < 3; ++tt) {
#pragma unroll
      for (int half = 0; half < 2; ++half) {
        int s = tt * 2 + half;                   // p = j
        bf16x8 av = *(const bf16x8*)(ap1 +
            (size_t)(((j * 6 + s) * 4 + w) * 64 + l) * 8);
        bf16x8 bv = *(const bf16x8*)&sval[tt][lr][half * 32 + lg * 8];
        acc = __builtin_amdgcn_mfma_f32_16x16x32_bf16(av, bv, acc, 0, 0, 0);
      }
    }
    if (j < 2) __syncthreads();                  // protect sval from next finish
  }

  // epilogue: bias + relu + store (oc = w*16+lg*4+i, px = lr in 4x4 tile)
  float4 bb = *(const float4*)&bdc[w * 16 + lg * 4];
  float bvv[4] = {bb.x, bb.y, bb.z, bb.w};
#pragma unroll
  for (int i = 0; i < 4; ++i) {
    int oc = w * 16 + lg * 4 + i;
    out[((size_t)(b * 64 + oc) * 96 + h0 + (lr >> 2)) * 96 + w0 + (lr & 3)] =
        fmaxf(acc[i] + bvv[i], 0.f);
  }
}

extern "C" void kernel_launch(void* const* d_in, const int* in_sizes, int n_in,
                              void* d_out, int out_size, void* d_ws, size_t ws_size,
                              hipStream_t stream) {
  const float* x = (const float*)d_in[0];
  const float* y = (const float*)d_in[1];
  const float* w_om = (const float*)d_in[2];
  const float* b_om = (const float*)d_in[3];
  const float* w_dc = (const float*)d_in[4];
  const float* b_dc = (const float*)d_in[5];
  float* out = (float*)d_out;

  float* om  = (float*)d_ws;                       // 1,990,656 f
  unsigned short* ap2 = (unsigned short*)(om + 1990656);   // 147,456 bf16
  unsigned short* ap1 = ap2 + 147456;              //  36,864 bf16
  unsigned short* ytbf = ap1 + 36864;              // 2,359,296 bf16

  prep_ytr_kernel<<<1296, 256, 0, stream>>>(w_om, w_dc, y, ap2, ap1, ytbf);
  conv_mfma_kernel<<<1152, 256, 0, stream>>>(x, ap2, b_om, om);
  deform_mfma_kernel<<<2304, 256, 0, stream>>>(ytbf, om, ap1, b_dc, out);
}